// Round 11
// baseline (448.967 us; speedup 1.0000x reference)
//
#include <hip/hip_runtime.h>

#define NXg   128
#define NYg   128
#define NSTA  24
#define NPICK 200000
#define INFV  1.0e6f
#define TS    8        // cells per thread per dim
#define TG    16       // tile grid is 16x16 tiles (256 threads)
#define RD    (TG + 2) // ring-padded tile-grid dim
#define MAXO  200      // safety cap on generations; early exit is exact
#define MAXP  12       // safety cap on passes per generation

// raw v_sqrt_f32 (~1 ulp) — skips the IEEE fixup chain
__device__ __forceinline__ float fsqrt_fast(float x) {
#if __has_builtin(__builtin_amdgcn_sqrtf)
  return __builtin_amdgcn_sqrtf(x);
#else
  float r; asm("v_sqrt_f32 %0, %1" : "=v"(r) : "v"(x)); return r;
#endif
}

// ---------------------------------------------------------------------------
// Eikonal: one block (256 threads) per (phase, station).
// Thread = 8x8 cell tile in registers; wave = 8x8 tile quadrant.
// Single-barrier generation loop (r10): double-buffered ring-padded edges +
// flags; every tile publishes unconditionally into the write buffer; the only
// sync is the __syncthreads_or termination vote.
// NEW (r11): within a generation, an awake wave iterates directional passes
// (adaptive order, dir = p ^ (k&3)) UNTIL A CLEAN PASS (local convergence
// w.r.t. current halos), not capped at 4. r5 showed total passes ~constant
// under schedule changes => fewer generations at the same pass budget =>
// the per-generation sync/publish tax (~20% of wall) is paid fewer times.
// Exactness: deterministic monotone operator, schedule-independent fixed
// point; gen chg = OR over passes; clean first pass everywhere certifies the
// global fixed point; wave skip as in r4. All exits exact.
// ---------------------------------------------------------------------------

template<int DR, int DC>
__device__ __forceinline__ void gs_pass(
    float (&u)[TS][TS], const float (&fh)[TS][TS], const float (&t2)[TS][TS],
    const float (&tpa)[TS], const float (&bta)[TS],
    const float (&lfa)[TS], const float (&rga)[TS], int &chg)
{
#pragma unroll
  for (int rr = 0; rr < TS; rr++) {
    const int r = (DR > 0) ? rr : (TS - 1 - rr);
#pragma unroll
    for (int cc = 0; cc < TS; cc++) {
      const int c = (DC > 0) ? cc : (TS - 1 - cc);
      const float up = (r == 0)      ? tpa[c] : u[r - 1][c];
      const float dn = (r == TS - 1) ? bta[c] : u[r + 1][c];
      const float lf = (c == 0)      ? lfa[r] : u[r][c - 1];
      const float rt = (c == TS - 1) ? rga[r] : u[r][c + 1];
      const float a  = fminf(up, dn);          // min x-neighbors (rows)
      const float b  = fminf(lf, rt);          // min y-neighbors (cols)
      const float dd = a - b;
      const float w  = fh[r][c];
      // no max(.,0) clamp: in the selected (two-sided) branch |dd|<w so the
      // sqrt arg > w^2 > 0; a NaN in the other branch is discarded by select.
      const float s  = __builtin_fmaf(-dd, dd, t2[r][c]);
      const float tw = 0.5f * ((a + b) + fsqrt_fast(s));
      const float on = fminf(a, b) + w;
      const float cand = (fabsf(dd) >= w) ? on : tw;
      const float old = u[r][c];
      chg |= (cand < old);
      u[r][c] = fminf(old, cand);
    }
  }
}

__global__ __launch_bounds__(256, 1) void eik_kernel(
    const float* __restrict__ vp, const float* __restrict__ vs,
    const float* __restrict__ station_loc, float* __restrict__ tab)
{
  // double-buffered ring-padded tile-edge arrays (ring stays INFV forever)
  __shared__ float eT[2][RD * RD][TS];
  __shared__ float eB[2][RD * RD][TS];
  __shared__ float eL[2][RD * RD][TS];
  __shared__ float eR[2][RD * RD][TS];
  // double-buffered per-tile change flags (ring stays 0 forever)
  __shared__ int flg[2][RD][RD];

  const int t    = threadIdx.x;
  const int wv   = t >> 6;
  const int lane = t & 63;
  // wave <-> 8x8-tile quadrant mapping (skip granularity = wave)
  const int ti = (wv >> 1) * 8 + (lane >> 3);
  const int tj = (wv & 1) * 8 + (lane & 7);
  const int fi = ti + 1, fj = tj + 1;
  const int rid = fi * RD + fj;

  const int blk = blockIdx.x;
  const int st = blk % NSTA;
  const int ph = blk / NSTA;
  const float* __restrict__ v = ph ? vs : vp;

  // init: all edge entries INFV (ring is never rewritten), all flags 0
  for (int i = t; i < 2 * RD * RD; i += 256) {
    const int b = i / (RD * RD), rem = i % (RD * RD);
    const float4 inf4 = make_float4(INFV, INFV, INFV, INFV);
    *reinterpret_cast<float4*>(&eT[b][rem][0]) = inf4;
    *reinterpret_cast<float4*>(&eT[b][rem][4]) = inf4;
    *reinterpret_cast<float4*>(&eB[b][rem][0]) = inf4;
    *reinterpret_cast<float4*>(&eB[b][rem][4]) = inf4;
    *reinterpret_cast<float4*>(&eL[b][rem][0]) = inf4;
    *reinterpret_cast<float4*>(&eL[b][rem][4]) = inf4;
    *reinterpret_cast<float4*>(&eR[b][rem][0]) = inf4;
    *reinterpret_cast<float4*>(&eR[b][rem][4]) = inf4;
    flg[b][rem / RD][rem % RD] = 0;
  }

  // source cell: round-half-even like jnp.round (H = 1)
  const float sx = station_loc[st * 3 + 0];
  const float sy = station_loc[st * 3 + 1];
  int ix = (int)rintf(sx); ix = ix < 0 ? 0 : (ix > NXg - 1 ? NXg - 1 : ix);
  int iy = (int)rintf(sy); iy = iy < 0 ? 0 : (iy > NYg - 1 ? NYg - 1 : iy);

  // primary pass direction points away from the source (wave-uniform,
  // deterministic => exact). dir: 0=(+,+) 1=(+,-) 2=(-,+) 3=(-,-)
  const int p = ((((wv >> 1) * 64 + 32) > ix) ? 0 : 2)
              | (((( wv & 1) * 64 + 32) > iy) ? 0 : 1);

  const int r0 = ti * TS, c0 = tj * TS;
  float u[TS][TS], fh[TS][TS], t2[TS][TS];
#pragma unroll
  for (int r = 0; r < TS; r++) {
    const float4 v0 = *reinterpret_cast<const float4*>(&v[(r0 + r) * NYg + c0]);
    const float4 v1 = *reinterpret_cast<const float4*>(&v[(r0 + r) * NYg + c0 + 4]);
    fh[r][0] = 1.0f / v0.x; fh[r][1] = 1.0f / v0.y;
    fh[r][2] = 1.0f / v0.z; fh[r][3] = 1.0f / v0.w;
    fh[r][4] = 1.0f / v1.x; fh[r][5] = 1.0f / v1.y;
    fh[r][6] = 1.0f / v1.z; fh[r][7] = 1.0f / v1.w;
#pragma unroll
    for (int c = 0; c < TS; c++) {
      t2[r][c] = (2.0f * fh[r][c]) * fh[r][c];
      u[r][c] = ((r0 + r) == ix && (c0 + c) == iy) ? 0.0f : INFV;
    }
  }

  auto publish = [&](int pb) {
    *reinterpret_cast<float4*>(&eT[pb][rid][0]) = make_float4(u[0][0], u[0][1], u[0][2], u[0][3]);
    *reinterpret_cast<float4*>(&eT[pb][rid][4]) = make_float4(u[0][4], u[0][5], u[0][6], u[0][7]);
    *reinterpret_cast<float4*>(&eB[pb][rid][0]) = make_float4(u[7][0], u[7][1], u[7][2], u[7][3]);
    *reinterpret_cast<float4*>(&eB[pb][rid][4]) = make_float4(u[7][4], u[7][5], u[7][6], u[7][7]);
    *reinterpret_cast<float4*>(&eL[pb][rid][0]) = make_float4(u[0][0], u[1][0], u[2][0], u[3][0]);
    *reinterpret_cast<float4*>(&eL[pb][rid][4]) = make_float4(u[4][0], u[5][0], u[6][0], u[7][0]);
    *reinterpret_cast<float4*>(&eR[pb][rid][0]) = make_float4(u[0][7], u[1][7], u[2][7], u[3][7]);
    *reinterpret_cast<float4*>(&eR[pb][rid][4]) = make_float4(u[4][7], u[5][7], u[6][7], u[7][7]);
  };

  // gen 0 reads buffer 0
  publish(0);
  flg[0][fi][fj] = 1;
  __syncthreads();

  for (int outer = 0; outer < MAXO; outer++) {
    const int rb = outer & 1;
    const int wb = 1 - rb;

    // ---- read phase (buffer rb) ----
    const int nb = flg[rb][fi][fj]
                 | flg[rb][fi - 1][fj] | flg[rb][fi + 1][fj]
                 | flg[rb][fi][fj - 1] | flg[rb][fi][fj + 1];
    int chg = 0;
    if (__any(nb)) {
      float tpa[TS], bta[TS], lfa[TS], rga[TS];
      {
        const float4 h0 = *reinterpret_cast<const float4*>(&eB[rb][rid - RD][0]);
        const float4 h1 = *reinterpret_cast<const float4*>(&eB[rb][rid - RD][4]);
        tpa[0] = h0.x; tpa[1] = h0.y; tpa[2] = h0.z; tpa[3] = h0.w;
        tpa[4] = h1.x; tpa[5] = h1.y; tpa[6] = h1.z; tpa[7] = h1.w;
      }
      {
        const float4 h0 = *reinterpret_cast<const float4*>(&eT[rb][rid + RD][0]);
        const float4 h1 = *reinterpret_cast<const float4*>(&eT[rb][rid + RD][4]);
        bta[0] = h0.x; bta[1] = h0.y; bta[2] = h0.z; bta[3] = h0.w;
        bta[4] = h1.x; bta[5] = h1.y; bta[6] = h1.z; bta[7] = h1.w;
      }
      {
        const float4 h0 = *reinterpret_cast<const float4*>(&eR[rb][rid - 1][0]);
        const float4 h1 = *reinterpret_cast<const float4*>(&eR[rb][rid - 1][4]);
        lfa[0] = h0.x; lfa[1] = h0.y; lfa[2] = h0.z; lfa[3] = h0.w;
        lfa[4] = h1.x; lfa[5] = h1.y; lfa[6] = h1.z; lfa[7] = h1.w;
      }
      {
        const float4 h0 = *reinterpret_cast<const float4*>(&eL[rb][rid + 1][0]);
        const float4 h1 = *reinterpret_cast<const float4*>(&eL[rb][rid + 1][4]);
        rga[0] = h0.x; rga[1] = h0.y; rga[2] = h0.z; rga[3] = h0.w;
        rga[4] = h1.x; rga[5] = h1.y; rga[6] = h1.z; rga[7] = h1.w;
      }

      // passes to local convergence: adaptive order (dir = p ^ (k&3)), exit
      // at first clean pass (direction-independent certificate). Same 4
      // gs_pass instantiations (no I$ bloat).
      for (int k = 0; k < MAXP; ++k) {
        int ck = 0;
        switch ((p ^ k) & 3) {
          case 0: gs_pass<+1, +1>(u, fh, t2, tpa, bta, lfa, rga, ck); break;
          case 1: gs_pass<+1, -1>(u, fh, t2, tpa, bta, lfa, rga, ck); break;
          case 2: gs_pass<-1, +1>(u, fh, t2, tpa, bta, lfa, rga, ck); break;
          default:gs_pass<-1, -1>(u, fh, t2, tpa, bta, lfa, rga, ck); break;
        }
        chg |= ck;
        if (!__any(ck)) break;
      }
    }

    // ---- write phase (buffer wb, disjoint from rb: no mid-barrier) ----
    publish(wb);
    flg[wb][fi][fj] = chg;

    if (!__syncthreads_or(chg)) break;
  }

  float* __restrict__ To = tab + (size_t)(ph * NSTA + st) * NXg * NYg;
#pragma unroll
  for (int r = 0; r < TS; r++) {
    *reinterpret_cast<float4*>(&To[(r0 + r) * NYg + c0]) =
        make_float4(u[r][0], u[r][1], u[r][2], u[r][3]);
    *reinterpret_cast<float4*>(&To[(r0 + r) * NYg + c0 + 4]) =
        make_float4(u[r][4], u[r][5], u[r][6], u[r][7]);
  }
}

// ---------------------------------------------------------------------------
// Picks: bilinear interp + arrival times + per-(station,phase) MSE pieces.
// ---------------------------------------------------------------------------
__global__ void picks_kernel(
    const float* __restrict__ evloc, const float* __restrict__ evtime,
    const int* __restrict__ pst, const int* __restrict__ pph,
    const int* __restrict__ pev, const float* __restrict__ ptime,
    const float* __restrict__ tab, float* __restrict__ out,
    float* __restrict__ acc)
{
  __shared__ float lsse[2 * NSTA];
  __shared__ float lcnt[2 * NSTA];
  if (threadIdx.x < 2 * NSTA) { lsse[threadIdx.x] = 0.0f; lcnt[threadIdx.x] = 0.0f; }
  __syncthreads();

  int i = blockIdx.x * blockDim.x + threadIdx.x;
  if (i < NPICK) {
    int e = pev[i], s = pst[i], p = pph[i];
    float x = evloc[e * 3 + 0];
    float y = evloc[e * 3 + 1];
    int ir0 = (int)floorf(x); ir0 = ir0 < 0 ? 0 : (ir0 > NXg - 2 ? NXg - 2 : ir0);
    int iz0 = (int)floorf(y); iz0 = iz0 < 0 ? 0 : (iz0 > NYg - 2 ? NYg - 2 : iz0);
    float xc = fminf(fmaxf(x, 0.0f), (float)(NXg - 1));
    float yc = fminf(fmaxf(y, 0.0f), (float)(NYg - 1));
    float r0f = (float)ir0, z0f = (float)iz0;
    float r1 = r0f + 1.0f, z1 = z0f + 1.0f;

    const float* Tb = tab + (size_t)(p * NSTA + s) * NXg * NYg;
    float Q00 = Tb[ir0 * NYg + iz0];
    float Q01 = Tb[ir0 * NYg + iz0 + 1];
    float Q10 = Tb[(ir0 + 1) * NYg + iz0];
    float Q11 = Tb[(ir0 + 1) * NYg + iz0 + 1];
    float tt = Q00 * (r1 - xc) * (z1 - yc) + Q10 * (xc - r0f) * (z1 - yc)
             + Q01 * (r1 - xc) * (yc - z0f) + Q11 * (xc - r0f) * (yc - z0f);
    float at = evtime[e] + tt;
    out[i] = at;

    float dq = at - ptime[i];
    int g = s * 2 + p;
    atomicAdd(&lsse[g], dq * dq);
    atomicAdd(&lcnt[g], 1.0f);
  }
  __syncthreads();
  if (threadIdx.x < 2 * NSTA) {
    atomicAdd(&acc[threadIdx.x], lsse[threadIdx.x]);
    atomicAdd(&acc[2 * NSTA + threadIdx.x], lcnt[threadIdx.x]);
  }
}

__global__ void loss_kernel(const float* __restrict__ acc, float* __restrict__ out)
{
  int l = threadIdx.x;
  float v = 0.0f;
  if (l < 2 * NSTA) v = acc[l] / fmaxf(acc[2 * NSTA + l], 1.0f);
#pragma unroll
  for (int o = 32; o > 0; o >>= 1) v += __shfl_down(v, o, 64);
  if (l == 0) out[NPICK] = v;
}

// ---------------------------------------------------------------------------
extern "C" void kernel_launch(void* const* d_in, const int* in_sizes, int n_in,
                              void* d_out, int out_size, void* d_ws, size_t ws_size,
                              hipStream_t stream)
{
  const float* vp           = (const float*)d_in[0];
  const float* vs           = (const float*)d_in[1];
  const float* station_loc  = (const float*)d_in[2];
  const float* event_loc    = (const float*)d_in[3];
  const float* event_time   = (const float*)d_in[4];
  const int*   pick_station = (const int*)d_in[5];
  const int*   pick_phase   = (const int*)d_in[6];
  const int*   pick_event   = (const int*)d_in[7];
  const float* phase_time   = (const float*)d_in[8];

  float* out = (float*)d_out;
  float* acc = (float*)d_ws;          // [0,48): sse, [48,96): cnt
  float* tab = acc + 256;             // 2*24*128*128 f32 travel-time tables

  hipMemsetAsync(d_ws, 0, 96 * sizeof(float), stream);

  eik_kernel<<<2 * NSTA, 256, 0, stream>>>(vp, vs, station_loc, tab);

  picks_kernel<<<(NPICK + 255) / 256, 256, 0, stream>>>(
      event_loc, event_time, pick_station, pick_phase, pick_event, phase_time,
      tab, out, acc);

  loss_kernel<<<1, 64, 0, stream>>>(acc, out);
}

// Round 12
// 298.609 us; speedup vs baseline: 1.5035x; 1.5035x over previous
//
#include <hip/hip_runtime.h>

#define NXg   128
#define NYg   128
#define NSTA  24
#define NPICK 200000
#define INFV  1.0e6f
#define TS    8        // cells per thread per dim
#define TG    16       // tile grid is 16x16 tiles (256 threads)
#define RD    (TG + 2) // ring-padded tile-grid dim
#define MAXO  200      // safety cap; early exit is exact

// raw v_sqrt_f32 (~1 ulp) — skips the IEEE fixup chain
__device__ __forceinline__ float fsqrt_fast(float x) {
#if __has_builtin(__builtin_amdgcn_sqrtf)
  return __builtin_amdgcn_sqrtf(x);
#else
  float r; asm("v_sqrt_f32 %0, %1" : "=v"(r) : "v"(x)); return r;
#endif
}

// ---------------------------------------------------------------------------
// Eikonal: one block (256 threads) per (phase, station).  [r10 structure —
// best verified: 292 us eik]
// Thread = 8x8 cell tile in registers; wave = 8x8 tile quadrant.
// Single-barrier generation loop: edges + flags double-buffered with an
// INFV/0 ring; EVERY tile publishes unconditionally into the write buffer
// each gen, so reads (buf rb) and writes (buf wb) never overlap and the only
// sync is the __syncthreads_or termination vote.
// Payload: adaptive pass order (k-th dir = p ^ k, p away from source, max 4),
// early exit at first clean pass (direction-independent certificate),
// wave-level skip when own + 4-neighbor flags are quiet. All exits exact.
// ---------------------------------------------------------------------------

template<int DR, int DC>
__device__ __forceinline__ void gs_pass(
    float (&u)[TS][TS], const float (&fh)[TS][TS], const float (&t2)[TS][TS],
    const float (&tpa)[TS], const float (&bta)[TS],
    const float (&lfa)[TS], const float (&rga)[TS], int &chg)
{
#pragma unroll
  for (int rr = 0; rr < TS; rr++) {
    const int r = (DR > 0) ? rr : (TS - 1 - rr);
#pragma unroll
    for (int cc = 0; cc < TS; cc++) {
      const int c = (DC > 0) ? cc : (TS - 1 - cc);
      const float up = (r == 0)      ? tpa[c] : u[r - 1][c];
      const float dn = (r == TS - 1) ? bta[c] : u[r + 1][c];
      const float lf = (c == 0)      ? lfa[r] : u[r][c - 1];
      const float rt = (c == TS - 1) ? rga[r] : u[r][c + 1];
      const float a  = fminf(up, dn);          // min x-neighbors (rows)
      const float b  = fminf(lf, rt);          // min y-neighbors (cols)
      const float dd = a - b;
      const float w  = fh[r][c];
      // no max(.,0) clamp: in the selected (two-sided) branch |dd|<w so the
      // sqrt arg > w^2 > 0; a NaN in the other branch is discarded by select.
      const float s  = __builtin_fmaf(-dd, dd, t2[r][c]);
      const float tw = 0.5f * ((a + b) + fsqrt_fast(s));
      const float on = fminf(a, b) + w;
      const float cand = (fabsf(dd) >= w) ? on : tw;
      const float old = u[r][c];
      chg |= (cand < old);
      u[r][c] = fminf(old, cand);
    }
  }
}

__global__ __launch_bounds__(256, 1) void eik_kernel(
    const float* __restrict__ vp, const float* __restrict__ vs,
    const float* __restrict__ station_loc, float* __restrict__ tab)
{
  // double-buffered ring-padded tile-edge arrays (ring stays INFV forever)
  __shared__ float eT[2][RD * RD][TS];
  __shared__ float eB[2][RD * RD][TS];
  __shared__ float eL[2][RD * RD][TS];
  __shared__ float eR[2][RD * RD][TS];
  // double-buffered per-tile change flags (ring stays 0 forever)
  __shared__ int flg[2][RD][RD];

  const int t    = threadIdx.x;
  const int wv   = t >> 6;
  const int lane = t & 63;
  // wave <-> 8x8-tile quadrant mapping (skip granularity = wave)
  const int ti = (wv >> 1) * 8 + (lane >> 3);
  const int tj = (wv & 1) * 8 + (lane & 7);
  const int fi = ti + 1, fj = tj + 1;
  const int rid = fi * RD + fj;

  const int blk = blockIdx.x;
  const int st = blk % NSTA;
  const int ph = blk / NSTA;
  const float* __restrict__ v = ph ? vs : vp;

  // init: all edge entries INFV (ring is never rewritten), all flags 0
  for (int i = t; i < 2 * RD * RD; i += 256) {
    const int b = i / (RD * RD), rem = i % (RD * RD);
    const float4 inf4 = make_float4(INFV, INFV, INFV, INFV);
    *reinterpret_cast<float4*>(&eT[b][rem][0]) = inf4;
    *reinterpret_cast<float4*>(&eT[b][rem][4]) = inf4;
    *reinterpret_cast<float4*>(&eB[b][rem][0]) = inf4;
    *reinterpret_cast<float4*>(&eB[b][rem][4]) = inf4;
    *reinterpret_cast<float4*>(&eL[b][rem][0]) = inf4;
    *reinterpret_cast<float4*>(&eL[b][rem][4]) = inf4;
    *reinterpret_cast<float4*>(&eR[b][rem][0]) = inf4;
    *reinterpret_cast<float4*>(&eR[b][rem][4]) = inf4;
    flg[b][rem / RD][rem % RD] = 0;
  }

  // source cell: round-half-even like jnp.round (H = 1)
  const float sx = station_loc[st * 3 + 0];
  const float sy = station_loc[st * 3 + 1];
  int ix = (int)rintf(sx); ix = ix < 0 ? 0 : (ix > NXg - 1 ? NXg - 1 : ix);
  int iy = (int)rintf(sy); iy = iy < 0 ? 0 : (iy > NYg - 1 ? NYg - 1 : iy);

  // primary pass direction points away from the source (wave-uniform,
  // deterministic => exact). dir: 0=(+,+) 1=(+,-) 2=(-,+) 3=(-,-)
  const int p = ((((wv >> 1) * 64 + 32) > ix) ? 0 : 2)
              | (((( wv & 1) * 64 + 32) > iy) ? 0 : 1);

  const int r0 = ti * TS, c0 = tj * TS;
  float u[TS][TS], fh[TS][TS], t2[TS][TS];
#pragma unroll
  for (int r = 0; r < TS; r++) {
    const float4 v0 = *reinterpret_cast<const float4*>(&v[(r0 + r) * NYg + c0]);
    const float4 v1 = *reinterpret_cast<const float4*>(&v[(r0 + r) * NYg + c0 + 4]);
    fh[r][0] = 1.0f / v0.x; fh[r][1] = 1.0f / v0.y;
    fh[r][2] = 1.0f / v0.z; fh[r][3] = 1.0f / v0.w;
    fh[r][4] = 1.0f / v1.x; fh[r][5] = 1.0f / v1.y;
    fh[r][6] = 1.0f / v1.z; fh[r][7] = 1.0f / v1.w;
#pragma unroll
    for (int c = 0; c < TS; c++) {
      t2[r][c] = (2.0f * fh[r][c]) * fh[r][c];
      u[r][c] = ((r0 + r) == ix && (c0 + c) == iy) ? 0.0f : INFV;
    }
  }

  auto publish = [&](int pb) {
    *reinterpret_cast<float4*>(&eT[pb][rid][0]) = make_float4(u[0][0], u[0][1], u[0][2], u[0][3]);
    *reinterpret_cast<float4*>(&eT[pb][rid][4]) = make_float4(u[0][4], u[0][5], u[0][6], u[0][7]);
    *reinterpret_cast<float4*>(&eB[pb][rid][0]) = make_float4(u[7][0], u[7][1], u[7][2], u[7][3]);
    *reinterpret_cast<float4*>(&eB[pb][rid][4]) = make_float4(u[7][4], u[7][5], u[7][6], u[7][7]);
    *reinterpret_cast<float4*>(&eL[pb][rid][0]) = make_float4(u[0][0], u[1][0], u[2][0], u[3][0]);
    *reinterpret_cast<float4*>(&eL[pb][rid][4]) = make_float4(u[4][0], u[5][0], u[6][0], u[7][0]);
    *reinterpret_cast<float4*>(&eR[pb][rid][0]) = make_float4(u[0][7], u[1][7], u[2][7], u[3][7]);
    *reinterpret_cast<float4*>(&eR[pb][rid][4]) = make_float4(u[4][7], u[5][7], u[6][7], u[7][7]);
  };

  // gen 0 reads buffer 0
  publish(0);
  flg[0][fi][fj] = 1;
  __syncthreads();

  for (int outer = 0; outer < MAXO; outer++) {
    const int rb = outer & 1;
    const int wb = 1 - rb;

    // ---- read phase (buffer rb) ----
    const int nb = flg[rb][fi][fj]
                 | flg[rb][fi - 1][fj] | flg[rb][fi + 1][fj]
                 | flg[rb][fi][fj - 1] | flg[rb][fi][fj + 1];
    int chg = 0;
    if (__any(nb)) {
      float tpa[TS], bta[TS], lfa[TS], rga[TS];
      {
        const float4 h0 = *reinterpret_cast<const float4*>(&eB[rb][rid - RD][0]);
        const float4 h1 = *reinterpret_cast<const float4*>(&eB[rb][rid - RD][4]);
        tpa[0] = h0.x; tpa[1] = h0.y; tpa[2] = h0.z; tpa[3] = h0.w;
        tpa[4] = h1.x; tpa[5] = h1.y; tpa[6] = h1.z; tpa[7] = h1.w;
      }
      {
        const float4 h0 = *reinterpret_cast<const float4*>(&eT[rb][rid + RD][0]);
        const float4 h1 = *reinterpret_cast<const float4*>(&eT[rb][rid + RD][4]);
        bta[0] = h0.x; bta[1] = h0.y; bta[2] = h0.z; bta[3] = h0.w;
        bta[4] = h1.x; bta[5] = h1.y; bta[6] = h1.z; bta[7] = h1.w;
      }
      {
        const float4 h0 = *reinterpret_cast<const float4*>(&eR[rb][rid - 1][0]);
        const float4 h1 = *reinterpret_cast<const float4*>(&eR[rb][rid - 1][4]);
        lfa[0] = h0.x; lfa[1] = h0.y; lfa[2] = h0.z; lfa[3] = h0.w;
        lfa[4] = h1.x; lfa[5] = h1.y; lfa[6] = h1.z; lfa[7] = h1.w;
      }
      {
        const float4 h0 = *reinterpret_cast<const float4*>(&eL[rb][rid + 1][0]);
        const float4 h1 = *reinterpret_cast<const float4*>(&eL[rb][rid + 1][4]);
        rga[0] = h0.x; rga[1] = h0.y; rga[2] = h0.z; rga[3] = h0.w;
        rga[4] = h1.x; rga[5] = h1.y; rga[6] = h1.z; rga[7] = h1.w;
      }

      // adaptive-order passes over the same 4 instantiations (no I$ bloat);
      // exit at first clean pass (direction-independent certificate)
      for (int k = 0; k < 4; ++k) {
        int ck = 0;
        switch (p ^ k) {
          case 0: gs_pass<+1, +1>(u, fh, t2, tpa, bta, lfa, rga, ck); break;
          case 1: gs_pass<+1, -1>(u, fh, t2, tpa, bta, lfa, rga, ck); break;
          case 2: gs_pass<-1, +1>(u, fh, t2, tpa, bta, lfa, rga, ck); break;
          default:gs_pass<-1, -1>(u, fh, t2, tpa, bta, lfa, rga, ck); break;
        }
        chg |= ck;
        if (!__any(ck)) break;
      }
    }

    // ---- write phase (buffer wb, disjoint from rb: no mid-barrier) ----
    publish(wb);
    flg[wb][fi][fj] = chg;

    if (!__syncthreads_or(chg)) break;
  }

  float* __restrict__ To = tab + (size_t)(ph * NSTA + st) * NXg * NYg;
#pragma unroll
  for (int r = 0; r < TS; r++) {
    *reinterpret_cast<float4*>(&To[(r0 + r) * NYg + c0]) =
        make_float4(u[r][0], u[r][1], u[r][2], u[r][3]);
    *reinterpret_cast<float4*>(&To[(r0 + r) * NYg + c0 + 4]) =
        make_float4(u[r][4], u[r][5], u[r][6], u[r][7]);
  }
}

// ---------------------------------------------------------------------------
// Picks: bilinear interp + arrival times + per-(station,phase) MSE pieces.
// ---------------------------------------------------------------------------
__global__ void picks_kernel(
    const float* __restrict__ evloc, const float* __restrict__ evtime,
    const int* __restrict__ pst, const int* __restrict__ pph,
    const int* __restrict__ pev, const float* __restrict__ ptime,
    const float* __restrict__ tab, float* __restrict__ out,
    float* __restrict__ acc)
{
  __shared__ float lsse[2 * NSTA];
  __shared__ float lcnt[2 * NSTA];
  if (threadIdx.x < 2 * NSTA) { lsse[threadIdx.x] = 0.0f; lcnt[threadIdx.x] = 0.0f; }
  __syncthreads();

  int i = blockIdx.x * blockDim.x + threadIdx.x;
  if (i < NPICK) {
    int e = pev[i], s = pst[i], p = pph[i];
    float x = evloc[e * 3 + 0];
    float y = evloc[e * 3 + 1];
    int ir0 = (int)floorf(x); ir0 = ir0 < 0 ? 0 : (ir0 > NXg - 2 ? NXg - 2 : ir0);
    int iz0 = (int)floorf(y); iz0 = iz0 < 0 ? 0 : (iz0 > NYg - 2 ? NYg - 2 : iz0);
    float xc = fminf(fmaxf(x, 0.0f), (float)(NXg - 1));
    float yc = fminf(fmaxf(y, 0.0f), (float)(NYg - 1));
    float r0f = (float)ir0, z0f = (float)iz0;
    float r1 = r0f + 1.0f, z1 = z0f + 1.0f;

    const float* Tb = tab + (size_t)(p * NSTA + s) * NXg * NYg;
    float Q00 = Tb[ir0 * NYg + iz0];
    float Q01 = Tb[ir0 * NYg + iz0 + 1];
    float Q10 = Tb[(ir0 + 1) * NYg + iz0];
    float Q11 = Tb[(ir0 + 1) * NYg + iz0 + 1];
    float tt = Q00 * (r1 - xc) * (z1 - yc) + Q10 * (xc - r0f) * (z1 - yc)
             + Q01 * (r1 - xc) * (yc - z0f) + Q11 * (xc - r0f) * (yc - z0f);
    float at = evtime[e] + tt;
    out[i] = at;

    float dq = at - ptime[i];
    int g = s * 2 + p;
    atomicAdd(&lsse[g], dq * dq);
    atomicAdd(&lcnt[g], 1.0f);
  }
  __syncthreads();
  if (threadIdx.x < 2 * NSTA) {
    atomicAdd(&acc[threadIdx.x], lsse[threadIdx.x]);
    atomicAdd(&acc[2 * NSTA + threadIdx.x], lcnt[threadIdx.x]);
  }
}

__global__ void loss_kernel(const float* __restrict__ acc, float* __restrict__ out)
{
  int l = threadIdx.x;
  float v = 0.0f;
  if (l < 2 * NSTA) v = acc[l] / fmaxf(acc[2 * NSTA + l], 1.0f);
#pragma unroll
  for (int o = 32; o > 0; o >>= 1) v += __shfl_down(v, o, 64);
  if (l == 0) out[NPICK] = v;
}

// ---------------------------------------------------------------------------
extern "C" void kernel_launch(void* const* d_in, const int* in_sizes, int n_in,
                              void* d_out, int out_size, void* d_ws, size_t ws_size,
                              hipStream_t stream)
{
  const float* vp           = (const float*)d_in[0];
  const float* vs           = (const float*)d_in[1];
  const float* station_loc  = (const float*)d_in[2];
  const float* event_loc    = (const float*)d_in[3];
  const float* event_time   = (const float*)d_in[4];
  const int*   pick_station = (const int*)d_in[5];
  const int*   pick_phase   = (const int*)d_in[6];
  const int*   pick_event   = (const int*)d_in[7];
  const float* phase_time   = (const float*)d_in[8];

  float* out = (float*)d_out;
  float* acc = (float*)d_ws;          // [0,48): sse, [48,96): cnt
  float* tab = acc + 256;             // 2*24*128*128 f32 travel-time tables

  hipMemsetAsync(d_ws, 0, 96 * sizeof(float), stream);

  eik_kernel<<<2 * NSTA, 256, 0, stream>>>(vp, vs, station_loc, tab);

  picks_kernel<<<(NPICK + 255) / 256, 256, 0, stream>>>(
      event_loc, event_time, pick_station, pick_phase, pick_event, phase_time,
      tab, out, acc);

  loss_kernel<<<1, 64, 0, stream>>>(acc, out);
}